// Round 2
// baseline (652.127 us; speedup 1.0000x reference)
//
#include <hip/hip_runtime.h>

// TopDownProjector: volume [B=2, C=1, H=512, W=512, D=256] f32, depth innermost.
// Per column: first non-zero scanning from d=255 downward.
//   height_field[col] = hit index (0 if empty)
//   seg_map[col]      = volume[col, hit] (0 if empty)
// d_out = [height_field (524288 f32) | seg_map (524288 f32)]
//
// R1 post-mortem: sparse top-of-column reads (one 128B line per 1KiB column)
// ran at ~280 GB/s useful — the 1KiB stride wrecks DRAM channel/row
// efficiency, costing nearly the same DRAM time as a full read but at 1/3
// the bandwidth. So go dense: one WAVE per column; 64 lanes x float4 = the
// whole 1024B column in one fully-coalesced load at streaming BW.
// Ballot+clz picks the highest non-zero index across the wave.

#define DDEPTH 256

__global__ __launch_bounds__(256)
void TopDownProjector_82806969467611_kernel(const float* __restrict__ vol,
                                            float* __restrict__ height,
                                            float* __restrict__ seg,
                                            int ncols) {
    int lane = threadIdx.x & 63;
    int wave = threadIdx.x >> 6;                  // 0..3 within block
    int col  = blockIdx.x * 4 + wave;             // one wave per column
    if (col >= ncols) return;

    // Lane l owns elements [4l, 4l+3] of the column: one dwordx4, and the
    // wave's 64 lanes cover the column's 1024 B contiguously.
    const float4* base = (const float4*)(vol + (size_t)col * DDEPTH);
    float4 v = base[lane];

    // Highest non-zero among this lane's 4 elements (prefer larger index).
    int   lidx = -1;
    float lval = 0.0f;
    if (v.x != 0.0f) { lidx = 4 * lane + 0; lval = v.x; }
    if (v.y != 0.0f) { lidx = 4 * lane + 1; lval = v.y; }
    if (v.z != 0.0f) { lidx = 4 * lane + 2; lval = v.z; }
    if (v.w != 0.0f) { lidx = 4 * lane + 3; lval = v.w; }

    // Wave-wide: winning lane = highest lane with any non-zero.
    unsigned long long ball = __ballot(lidx >= 0);
    float h = 0.0f, s = 0.0f;
    if (ball != 0ull) {
        int win = 63 - __clzll(ball);
        h = (float)__shfl(lidx, win);
        s = __shfl(lval, win);
    }

    if (lane == 0) {
        height[col] = h;
        seg[col]    = s;
    }
}

extern "C" void kernel_launch(void* const* d_in, const int* in_sizes, int n_in,
                              void* d_out, int out_size, void* d_ws, size_t ws_size,
                              hipStream_t stream) {
    const float* vol = (const float*)d_in[0];
    float* out = (float*)d_out;

    int ncols = in_sizes[0] / DDEPTH;      // 524288
    float* height = out;                   // first output plane
    float* seg    = out + ncols;           // second output plane

    int block = 256;                       // 4 waves = 4 columns per block
    int grid = (ncols + 3) / 4;
    TopDownProjector_82806969467611_kernel<<<grid, block, 0, stream>>>(
        vol, height, seg, ncols);
}

// Round 3
// 569.020 us; speedup vs baseline: 1.1461x; 1.1461x over previous
//
#include <hip/hip_runtime.h>

// TopDownProjector: volume [B=2, C=1, H=512, W=512, D=256] f32, depth innermost.
// Per column: first non-zero scanning from d=255 downward.
//   d_out = [height_field (524288 f32) | seg_map (524288 f32)]
//
// R2 post-mortem: dense full-column read (512 MiB) = ~152 us kernel; sparse
// top-of-column read (R1, 64 MiB scattered) = ~72 us kernel. dur_us includes
// ~500 us of fixed harness reset (2.1 GiB ws poison + d_in restore), so the
// kernel is the only movable part. Sparse wins: revert to one thread/column.
//
// R3 experiment: is the sparse kernel byte-bound or touch-bound?
//  - First probe is a single 4 B nontemporal load at d=255 (resolves 8/9 of
//    columns). If HBM fetch granule < 128 B, traffic halves vs the 16 B probe.
//  - Fallback float4 scan only for columns with v[255]==0 (1/9).
//  - Nontemporal loads/stores: single-touch data, skip L2/L3 allocation.

#define DDEPTH 256

__global__ __launch_bounds__(256)
void TopDownProjector_82806969467611_kernel(const float* __restrict__ vol,
                                            float* __restrict__ height,
                                            float* __restrict__ seg,
                                            int ncols) {
    int col = blockIdx.x * blockDim.x + threadIdx.x;
    if (col >= ncols) return;

    const float* cp = vol + (size_t)col * DDEPTH;

    float h, s;
    float v255 = __builtin_nontemporal_load(cp + (DDEPTH - 1));
    if (v255 != 0.0f) {
        h = (float)(DDEPTH - 1);
        s = v255;
    } else {
        h = 0.0f;
        s = 0.0f;
        const float4* base = (const float4*)cp;
        #pragma unroll 1
        for (int q = DDEPTH / 4 - 1; q >= 0; --q) {
            float4 v = base[q];
            if (v.x != 0.0f || v.y != 0.0f || v.z != 0.0f || v.w != 0.0f) {
                int idx;
                float val;
                if (v.w != 0.0f)      { idx = q * 4 + 3; val = v.w; }
                else if (v.z != 0.0f) { idx = q * 4 + 2; val = v.z; }
                else if (v.y != 0.0f) { idx = q * 4 + 1; val = v.y; }
                else                  { idx = q * 4 + 0; val = v.x; }
                h = (float)idx;
                s = val;
                break;
            }
        }
    }

    __builtin_nontemporal_store(h, height + col);
    __builtin_nontemporal_store(s, seg + col);
}

extern "C" void kernel_launch(void* const* d_in, const int* in_sizes, int n_in,
                              void* d_out, int out_size, void* d_ws, size_t ws_size,
                              hipStream_t stream) {
    const float* vol = (const float*)d_in[0];
    float* out = (float*)d_out;

    int ncols = in_sizes[0] / DDEPTH;      // 524288
    float* height = out;                   // first output plane
    float* seg    = out + ncols;           // second output plane

    int block = 256;
    int grid = (ncols + block - 1) / block;
    TopDownProjector_82806969467611_kernel<<<grid, block, 0, stream>>>(
        vol, height, seg, ncols);
}